// Round 14
// baseline (467.556 us; speedup 1.0000x reference)
//
#include <hip/hip_runtime.h>
#include <hip/hip_bf16.h>

#define HID 64
#define DIN 128
#define NCLS 4

__device__ __forceinline__ float bcast(float v, int l) {
    return __uint_as_float(__builtin_amdgcn_readlane(__float_as_uint(v), l));
}
__device__ __forceinline__ ushort f2bf(float f) {            // fp32 -> bf16 RNE
    unsigned u = __float_as_uint(f);
    return (ushort)((u + 0x7fffu + ((u >> 16) & 1u)) >> 16);
}
__device__ __forceinline__ float bflo(unsigned v) { return __uint_as_float(v << 16); }
__device__ __forceinline__ float bfhi(unsigned v) { return __uint_as_float(v & 0xffff0000u); }

// ============ CSR build ============
// pk[d] packs {cnt:24 | deg_fp:40} (scale 2^20); one u64 atomic per edge,
// returned high bits = this edge's rank within its dst bucket.

__global__ __launch_bounds__(256) void degrank_kernel(const float* __restrict__ ea,
                                                      const int* __restrict__ dst,
                                                      const float* __restrict__ We,
                                                      const float* __restrict__ be,
                                                      unsigned long long* __restrict__ pk,
                                                      int* __restrict__ rank, int E) {
    int e = blockIdx.x * blockDim.x + threadIdx.x;
    if (e >= E) return;
    float ew = ea[e] * We[0] + be[0];
    unsigned long long fx = (unsigned long long)(ew * 1048576.0f + 0.5f);
    unsigned long long old = atomicAdd(&pk[dst[e]], (1ull << 40) | fx);
    rank[e] = (int)(old >> 40);
}

__global__ __launch_bounds__(256) void unpack_scan1_kernel(const unsigned long long* __restrict__ pk,
                                                           float* __restrict__ dinv,
                                                           int* __restrict__ scanned,
                                                           int* __restrict__ bsum, int N) {
    int t = blockIdx.x * 256 + threadIdx.x;
    int lane = threadIdx.x & 63, w = threadIdx.x >> 6;
    int cnt = 0;
    if (t < N) {
        unsigned long long v = pk[t];
        cnt = (int)(v >> 40);
        float deg = (float)((double)(v & ((1ull << 40) - 1)) * (1.0 / 1048576.0));
        dinv[t] = rsqrtf(deg + 1.0f);      // self-loop weight 1.0
    }
    int xv = cnt;
#pragma unroll
    for (int off = 1; off < 64; off <<= 1) {
        int y = __shfl_up(xv, off);
        if (lane >= off) xv += y;
    }
    __shared__ int ws_[4];
    if (lane == 63) ws_[w] = xv;
    __syncthreads();
    for (int i = 0; i < w; ++i) xv += ws_[i];
    if (t < N) scanned[t] = xv;
    if (threadIdx.x == 255) bsum[blockIdx.x] = xv;
}

__global__ __launch_bounds__(1024) void scan2_kernel(int* __restrict__ bsum, int nb) {
    int t = threadIdx.x, lane = t & 63, w = t >> 6;
    int x = (t < nb) ? bsum[t] : 0;
#pragma unroll
    for (int off = 1; off < 64; off <<= 1) {
        int y = __shfl_up(x, off);
        if (lane >= off) x += y;
    }
    __shared__ int s16[16];
    if (lane == 63) s16[w] = x;
    __syncthreads();
    if (w == 0) {
        int y = (lane < 16) ? s16[lane] : 0;
#pragma unroll
        for (int off = 1; off < 16; off <<= 1) {
            int z = __shfl_up(y, off);
            if (lane >= off) y += z;
        }
        if (lane < 16) s16[lane] = y;
    }
    __syncthreads();
    if (w > 0) x += s16[w - 1];
    if (t < nb) bsum[t] = x;
}

__global__ __launch_bounds__(256) void scan3_kernel(const int* __restrict__ scanned,
                                                    const int* __restrict__ bsum,
                                                    int* __restrict__ rowptr, int N) {
    int t = blockIdx.x * 256 + threadIdx.x;
    if (t >= N) return;
    int add = (blockIdx.x > 0) ? bsum[blockIdx.x - 1] : 0;
    rowptr[t + 1] = scanned[t] + add;
    if (t == 0) rowptr[0] = 0;
}

// atomic-free fill: slot = rowptr[dst] + rank; stores {src, ew}
__global__ __launch_bounds__(256) void fill_kernel(const float* __restrict__ ea,
                                                   const int* __restrict__ src,
                                                   const int* __restrict__ dst,
                                                   const int* __restrict__ rank,
                                                   const float* __restrict__ We,
                                                   const float* __restrict__ be,
                                                   const int* __restrict__ rowptr,
                                                   float2* __restrict__ srcnorm, int E) {
    int e = blockIdx.x * blockDim.x + threadIdx.x;
    if (e >= E) return;
    float ew = ea[e] * We[0] + be[0];
    int d = dst[e];
    srcnorm[rowptr[d] + rank[e]] = make_float2(__int_as_float(src[e]), ew);
}

// ============ input proj: h1 = relu(x@Win+b) (f32) and hs1 = h1*dinv (bf16) ============

__global__ __launch_bounds__(256) void inproj_kernel(const float* __restrict__ x,
                                                     const float* __restrict__ W,
                                                     const float* __restrict__ b,
                                                     const float* __restrict__ dinv,
                                                     float* __restrict__ h,
                                                     unsigned* __restrict__ hs, int N) {
    int lane = threadIdx.x & 63;
    int gw = (blockIdx.x * 256 + threadIdx.x) >> 6;
    int n0 = gw * 4;
    if (n0 >= N) return;
    const float* xr[4];
    float acc[4], dnv[4];
    float bc = b[lane];
#pragma unroll
    for (int j = 0; j < 4; ++j) {
        int n = n0 + j; if (n >= N) n = N - 1;
        xr[j] = x + (long)__builtin_amdgcn_readfirstlane(n) * DIN;  // uniform -> s_load
        acc[j] = bc;
        dnv[j] = dinv[n];
    }
#pragma unroll 16
    for (int k = 0; k < DIN; ++k) {
        float wv = W[k * HID + lane];
#pragma unroll
        for (int j = 0; j < 4; ++j)
            acc[j] = fmaf(xr[j][k], wv, acc[j]);
    }
#pragma unroll
    for (int j = 0; j < 4; ++j) {
        int n = n0 + j;
        if (n < N) {
            float hv = fmaxf(acc[j], 0.0f);
            h[((long)n << 6) | lane] = hv;
            unsigned bv = f2bf(hv * dnv[j]);
            unsigned nb = __shfl_xor(bv, 1);
            if ((lane & 1) == 0)
                hs[(unsigned)n * 32 + (lane >> 1)] = bv | (nb << 16);
        }
    }
}

// ============ pure gather: s[n] = dinv[n]*(sum ew*hs[src] + hs[n]) ============

__global__ __launch_bounds__(256) void gather_kernel(const int* __restrict__ rowptr,
                                                     const float2* __restrict__ srcnorm,
                                                     const unsigned* __restrict__ hs,
                                                     const float* __restrict__ dinv,
                                                     float* __restrict__ s, int N) {
    int t = blockIdx.x * blockDim.x + threadIdx.x;
    int lane = t & 63;
    int c2 = lane & 31, hf = lane >> 5;
    int n = __builtin_amdgcn_readfirstlane(t >> 6);   // wave-uniform node id
    if (n >= N) return;
    unsigned sv = hs[(unsigned)n * 32 + c2];
    float ax = hf ? 0.0f : bflo(sv);                  // self term, half 0 only
    float ay = hf ? 0.0f : bfhi(sv);
    int beg = rowptr[n], end = rowptr[n + 1];         // uniform -> s_load
    int i = beg;
    int end16 = beg + ((end - beg) & ~15);
    for (; i < end16; i += 16) {                      // 16 edges: 8 per half
        float2 p0 = srcnorm[i + hf],      p1 = srcnorm[i + 2 + hf];
        float2 p2 = srcnorm[i + 4 + hf],  p3 = srcnorm[i + 6 + hf];
        float2 p4 = srcnorm[i + 8 + hf],  p5 = srcnorm[i + 10 + hf];
        float2 p6 = srcnorm[i + 12 + hf], p7 = srcnorm[i + 14 + hf];
        unsigned v0 = hs[(unsigned)__float_as_int(p0.x) * 32 + c2];
        unsigned v1 = hs[(unsigned)__float_as_int(p1.x) * 32 + c2];
        unsigned v2 = hs[(unsigned)__float_as_int(p2.x) * 32 + c2];
        unsigned v3 = hs[(unsigned)__float_as_int(p3.x) * 32 + c2];
        unsigned v4 = hs[(unsigned)__float_as_int(p4.x) * 32 + c2];
        unsigned v5 = hs[(unsigned)__float_as_int(p5.x) * 32 + c2];
        unsigned v6 = hs[(unsigned)__float_as_int(p6.x) * 32 + c2];
        unsigned v7 = hs[(unsigned)__float_as_int(p7.x) * 32 + c2];
        ax = fmaf(bflo(v0), p0.y, ax); ay = fmaf(bfhi(v0), p0.y, ay);
        ax = fmaf(bflo(v1), p1.y, ax); ay = fmaf(bfhi(v1), p1.y, ay);
        ax = fmaf(bflo(v2), p2.y, ax); ay = fmaf(bfhi(v2), p2.y, ay);
        ax = fmaf(bflo(v3), p3.y, ax); ay = fmaf(bfhi(v3), p3.y, ay);
        ax = fmaf(bflo(v4), p4.y, ax); ay = fmaf(bfhi(v4), p4.y, ay);
        ax = fmaf(bflo(v5), p5.y, ax); ay = fmaf(bfhi(v5), p5.y, ay);
        ax = fmaf(bflo(v6), p6.y, ax); ay = fmaf(bfhi(v6), p6.y, ay);
        ax = fmaf(bflo(v7), p7.y, ax); ay = fmaf(bfhi(v7), p7.y, ay);
    }
    int end8 = i + ((end - i) & ~7);
    for (; i < end8; i += 8) {
        float2 pa = srcnorm[i + hf],     pb = srcnorm[i + 2 + hf];
        float2 pc = srcnorm[i + 4 + hf], pd = srcnorm[i + 6 + hf];
        unsigned va = hs[(unsigned)__float_as_int(pa.x) * 32 + c2];
        unsigned vb = hs[(unsigned)__float_as_int(pb.x) * 32 + c2];
        unsigned vc = hs[(unsigned)__float_as_int(pc.x) * 32 + c2];
        unsigned vd = hs[(unsigned)__float_as_int(pd.x) * 32 + c2];
        ax = fmaf(bflo(va), pa.y, ax); ay = fmaf(bfhi(va), pa.y, ay);
        ax = fmaf(bflo(vb), pb.y, ax); ay = fmaf(bfhi(vb), pb.y, ay);
        ax = fmaf(bflo(vc), pc.y, ax); ay = fmaf(bfhi(vc), pc.y, ay);
        ax = fmaf(bflo(vd), pd.y, ax); ay = fmaf(bfhi(vd), pd.y, ay);
    }
    for (; i < end; i += 2) {
        int ia = i + hf;
        if (ia < end) {
            float2 p = srcnorm[ia];
            unsigned v = hs[(unsigned)__float_as_int(p.x) * 32 + c2];
            ax = fmaf(bflo(v), p.y, ax);
            ay = fmaf(bfhi(v), p.y, ay);
        }
    }
    ax += __shfl_xor(ax, 32);                         // combine halves
    ay += __shfl_xor(ay, 32);
    if (hf == 0) {
        float dn = dinv[n];
        ((float2*)(s + ((long)n << 6)))[c2] = make_float2(ax * dn, ay * dn);
    }
}

// ============ dense layer, 2-stage software pipeline ============
// out = LN(s@W + b) relu (+res) -> h [, hs_next]; next group's loads issue
// before the current group's FMA chain so L2/L3 latency hides under compute.

__device__ __forceinline__ void dense_load(const float* __restrict__ s,
                                           const float* __restrict__ h,
                                           const float* __restrict__ dinv,
                                           int add_res, int withhs,
                                           int n0, int N, int lane,
                                           float* sv, float* rv, float* dnv) {
#pragma unroll
    for (int j = 0; j < 4; ++j) {
        int n = n0 + j; if (n >= N) n = N - 1;
        sv[j] = s[((long)n << 6) | lane];
        rv[j] = add_res ? h[((long)n << 6) | lane] : 0.0f;
        dnv[j] = withhs ? dinv[n] : 0.0f;
    }
}

__global__ __launch_bounds__(256) void dense_kernel(const float* __restrict__ s,
                                                    const float* __restrict__ Wg,
                                                    const float* __restrict__ bg,
                                                    const float* __restrict__ dinv,
                                                    float* __restrict__ h,
                                                    unsigned* __restrict__ hs,
                                                    int add_res, int N) {
    int lane = threadIdx.x & 63;
    int gw = blockIdx.x * 4 + ((int)threadIdx.x >> 6);
    int stride = gridDim.x * 4 * 4;                   // nodes per generation
    int withhs = (hs != nullptr);
    float wcol[64];
#pragma unroll
    for (int k = 0; k < 64; ++k) wcol[k] = Wg[k * HID + lane];
    float bgl = bg[lane];
    int n0 = gw * 4;
    if (n0 >= N) return;
    float sv[4], rv[4], dnv[4];
    dense_load(s, h, dinv, add_res, withhs, n0, N, lane, sv, rv, dnv);
    while (true) {
        int n1 = n0 + stride;
        bool more = (n1 < N);
        float sv2[4], rv2[4], dnv2[4];
        if (more)                                     // prefetch next group
            dense_load(s, h, dinv, add_res, withhs, n1, N, lane, sv2, rv2, dnv2);
        float acc[4];
#pragma unroll
        for (int j = 0; j < 4; ++j) acc[j] = bgl;
#pragma unroll
        for (int k = 0; k < 64; ++k) {
#pragma unroll
            for (int j = 0; j < 4; ++j)
                acc[j] = fmaf(bcast(sv[j], k), wcol[k], acc[j]);
        }
        float s1[4], s2[4];
#pragma unroll
        for (int j = 0; j < 4; ++j) { s1[j] = acc[j]; s2[j] = acc[j] * acc[j]; }
#pragma unroll
        for (int off = 32; off; off >>= 1) {
#pragma unroll
            for (int j = 0; j < 4; ++j) {
                s1[j] += __shfl_xor(s1[j], off);
                s2[j] += __shfl_xor(s2[j], off);
            }
        }
#pragma unroll
        for (int j = 0; j < 4; ++j) {
            int n = n0 + j;
            float mean = s1[j] * (1.0f / 64.0f);
            float var  = s2[j] * (1.0f / 64.0f) - mean * mean;
            float o = fmaxf((acc[j] - mean) * rsqrtf(var + 1e-5f), 0.0f) + rv[j];
            if (n < N) {
                h[((long)n << 6) | lane] = o;
                if (withhs) {
                    unsigned bv = f2bf(o * dnv[j]);
                    unsigned nb = __shfl_xor(bv, 1);
                    if ((lane & 1) == 0)
                        hs[(unsigned)n * 32 + (lane >> 1)] = bv | (nb << 16);
                }
            }
        }
        if (!more) break;
        n0 = n1;
#pragma unroll
        for (int j = 0; j < 4; ++j) { sv[j] = sv2[j]; rv[j] = rv2[j]; dnv[j] = dnv2[j]; }
    }
}

// ============ fused heads: weights in registers, grid-stride, pipelined ============

__global__ __launch_bounds__(256) void head_kernel(const float* __restrict__ h,
                                                   const float* __restrict__ Wa1,
                                                   const float* __restrict__ ba1,
                                                   const float* __restrict__ Wa2,
                                                   const float* __restrict__ ba2,
                                                   const float* __restrict__ Wc1,
                                                   const float* __restrict__ bc1,
                                                   const float* __restrict__ Wc2,
                                                   const float* __restrict__ bc2,
                                                   float* __restrict__ out, int N) {
    __shared__ float hsm[4][HID];
    int lane = threadIdx.x & 63, w = threadIdx.x >> 6;
    int jj = lane & 31, hf = lane >> 5;
    float wa1[32], wc1[32];
#pragma unroll
    for (int k = 0; k < 32; ++k) {
        int kk = hf * 32 + k;
        wa1[k] = Wa1[kk * 32 + jj];
        wc1[k] = Wc1[kk * 32 + jj];
    }
    float wa2v = Wa2[jj], ba1v = ba1[jj], ba2v = ba2[0], bc1v = bc1[jj];
    float wc2v[4], bc2v[4];
#pragma unroll
    for (int c = 0; c < 4; ++c) { wc2v[c] = Wc2[jj * 4 + c]; bc2v[c] = bc2[c]; }
    int gw = blockIdx.x * 4 + w, stride = gridDim.x * 4;
    if (gw >= N) return;
    float hv = h[((long)gw << 6) | lane];
    for (int n = gw; n < N; n += stride) {
        int n1 = n + stride;
        float hv2 = 0.0f;
        if (n1 < N) hv2 = h[((long)n1 << 6) | lane];  // prefetch next node row
        hsm[w][lane] = hv;
        float a1p = 0.0f, c1p = 0.0f;
#pragma unroll
        for (int k = 0; k < 32; ++k) {
            float hk = hsm[w][hf * 32 + k];
            a1p = fmaf(hk, wa1[k], a1p);
            c1p = fmaf(hk, wc1[k], c1p);
        }
        a1p += __shfl_xor(a1p, 32);
        c1p += __shfl_xor(c1p, 32);
        float a1 = fmaxf(a1p + ba1v, 0.0f);
        float z = a1 * wa2v;
#pragma unroll
        for (int off = 16; off; off >>= 1) z += __shfl_xor(z, off);
        float attn = 1.0f / (1.0f + expf(-(z + ba2v)));
        float c1 = fmaxf(fmaf(attn, c1p, bc1v), 0.0f);
        float o0 = c1 * wc2v[0], o1 = c1 * wc2v[1], o2 = c1 * wc2v[2], o3 = c1 * wc2v[3];
#pragma unroll
        for (int off = 16; off; off >>= 1) {
            o0 += __shfl_xor(o0, off);
            o1 += __shfl_xor(o1, off);
            o2 += __shfl_xor(o2, off);
            o3 += __shfl_xor(o3, off);
        }
        if (lane == 0) {
            float4 ov = make_float4(o0 + bc2v[0], o1 + bc2v[1], o2 + bc2v[2], o3 + bc2v[3]);
            *(float4*)(out + (long)n * NCLS) = ov;
            out[(long)N * NCLS + n] = attn;
        }
        hv = hv2;
    }
}

// ============ launcher ============

extern "C" void kernel_launch(void* const* d_in, const int* in_sizes, int n_in,
                              void* d_out, int out_size, void* d_ws, size_t ws_size,
                              hipStream_t stream) {
    const float* x    = (const float*)d_in[0];
    const float* ea   = (const float*)d_in[1];
    const int*   ei   = (const int*)d_in[2];
    const float* We   = (const float*)d_in[3];
    const float* be   = (const float*)d_in[4];
    const float* W_in = (const float*)d_in[5];
    const float* b_in = (const float*)d_in[6];
    const float* W_g  = (const float*)d_in[7];
    const float* b_g  = (const float*)d_in[8];
    const float* Wa1  = (const float*)d_in[9];
    const float* ba1  = (const float*)d_in[10];
    const float* Wa2  = (const float*)d_in[11];
    const float* ba2  = (const float*)d_in[12];
    const float* Wc1  = (const float*)d_in[13];
    const float* bc1  = (const float*)d_in[14];
    const float* Wc2  = (const float*)d_in[15];
    const float* bc2  = (const float*)d_in[16];
    float* out = (float*)d_out;

    const int N = in_sizes[0] / DIN;       // 100000
    const int E = in_sizes[1];             // 1600000
    const int* srcI = ei;
    const int* dstI = ei + E;
    const int nblk = (N + 255) / 256;      // 391 <= 1024

    unsigned long long* pk = (unsigned long long*)d_ws;     // N u64
    float*    dinv    = (float*)(pk + N);                   // N f32
    float*    h       = dinv + N;                           // N*64 f32
    float*    s       = h + (long)N * HID;                  // N*64 f32
    unsigned* hs      = (unsigned*)(s + (long)N * HID);     // N*32 u32 (bf16 pairs)
    float2*   srcnorm = (float2*)(hs + (long)N * 32);       // E float2 (8B-aligned)
    int*      scanned = (int*)(srcnorm + E);                // N
    int*      bsum    = scanned + N;                        // 1024
    int*      rowptr  = bsum + 1024;                        // N+1
    int*      rank    = rowptr + N + 1;                     // E

    hipMemsetAsync(pk, 0, N * sizeof(unsigned long long), stream);

    degrank_kernel<<<(E + 255) / 256, 256, 0, stream>>>(ea, dstI, We, be, pk, rank, E);
    unpack_scan1_kernel<<<nblk, 256, 0, stream>>>(pk, dinv, scanned, bsum, N);
    scan2_kernel<<<1, 1024, 0, stream>>>(bsum, nblk);
    scan3_kernel<<<nblk, 256, 0, stream>>>(scanned, bsum, rowptr, N);
    fill_kernel<<<(E + 255) / 256, 256, 0, stream>>>(ea, srcI, dstI, rank, We, be,
                                                     rowptr, srcnorm, E);

    inproj_kernel<<<(N + 15) / 16, 256, 0, stream>>>(x, W_in, b_in, dinv, h, hs, N);

    long nt = (long)N * HID;
    // layer 0: gather(hs1) -> s ; dense: LN(s@W0+b0) -> h2, hs2 (no residual)
    gather_kernel<<<(nt + 255) / 256, 256, 0, stream>>>(rowptr, srcnorm, hs, dinv, s, N);
    dense_kernel<<<2048, 256, 0, stream>>>(s, W_g, b_g, dinv, h, hs, 0, N);
    // layer 1: residual
    gather_kernel<<<(nt + 255) / 256, 256, 0, stream>>>(rowptr, srcnorm, hs, dinv, s, N);
    dense_kernel<<<2048, 256, 0, stream>>>(s, W_g + HID * HID, b_g + HID, dinv, h, hs, 1, N);
    // layer 2: dense (no hs), then standalone head
    gather_kernel<<<(nt + 255) / 256, 256, 0, stream>>>(rowptr, srcnorm, hs, dinv, s, N);
    dense_kernel<<<2048, 256, 0, stream>>>(s, W_g + 2 * HID * HID, b_g + 2 * HID, dinv,
                                           h, (unsigned*)nullptr, 1, N);
    head_kernel<<<1024, 256, 0, stream>>>(h, Wa1, ba1, Wa2, ba2,
                                          Wc1, bc1, Wc2, bc2, out, N);
}

// Round 15
// 460.027 us; speedup vs baseline: 1.0164x; 1.0164x over previous
//
#include <hip/hip_runtime.h>
#include <hip/hip_bf16.h>

#define HID 64
#define DIN 128
#define NCLS 4

__device__ __forceinline__ float bcast(float v, int l) {
    return __uint_as_float(__builtin_amdgcn_readlane(__float_as_uint(v), l));
}
__device__ __forceinline__ ushort f2bf(float f) {            // fp32 -> bf16 RNE
    unsigned u = __float_as_uint(f);
    return (ushort)((u + 0x7fffu + ((u >> 16) & 1u)) >> 16);
}
__device__ __forceinline__ float bflo(unsigned v) { return __uint_as_float(v << 16); }
__device__ __forceinline__ float bfhi(unsigned v) { return __uint_as_float(v & 0xffff0000u); }

// ============ CSR build ============
// pk[d] packs {cnt:24 | deg_fp:40} (scale 2^20); one u64 atomic per edge,
// returned high bits = this edge's rank within its dst bucket.

__global__ __launch_bounds__(256) void degrank_kernel(const float* __restrict__ ea,
                                                      const int* __restrict__ dst,
                                                      const float* __restrict__ We,
                                                      const float* __restrict__ be,
                                                      unsigned long long* __restrict__ pk,
                                                      int* __restrict__ rank, int E) {
    int e = blockIdx.x * blockDim.x + threadIdx.x;
    if (e >= E) return;
    float ew = ea[e] * We[0] + be[0];
    unsigned long long fx = (unsigned long long)(ew * 1048576.0f + 0.5f);
    unsigned long long old = atomicAdd(&pk[dst[e]], (1ull << 40) | fx);
    rank[e] = (int)(old >> 40);
}

__global__ __launch_bounds__(256) void unpack_scan1_kernel(const unsigned long long* __restrict__ pk,
                                                           float* __restrict__ dinv,
                                                           int* __restrict__ scanned,
                                                           int* __restrict__ bsum, int N) {
    int t = blockIdx.x * 256 + threadIdx.x;
    int lane = threadIdx.x & 63, w = threadIdx.x >> 6;
    int cnt = 0;
    if (t < N) {
        unsigned long long v = pk[t];
        cnt = (int)(v >> 40);
        float deg = (float)((double)(v & ((1ull << 40) - 1)) * (1.0 / 1048576.0));
        dinv[t] = rsqrtf(deg + 1.0f);      // self-loop weight 1.0
    }
    int xv = cnt;
#pragma unroll
    for (int off = 1; off < 64; off <<= 1) {
        int y = __shfl_up(xv, off);
        if (lane >= off) xv += y;
    }
    __shared__ int ws_[4];
    if (lane == 63) ws_[w] = xv;
    __syncthreads();
    for (int i = 0; i < w; ++i) xv += ws_[i];
    if (t < N) scanned[t] = xv;
    if (threadIdx.x == 255) bsum[blockIdx.x] = xv;
}

__global__ __launch_bounds__(1024) void scan2_kernel(int* __restrict__ bsum, int nb) {
    int t = threadIdx.x, lane = t & 63, w = t >> 6;
    int x = (t < nb) ? bsum[t] : 0;
#pragma unroll
    for (int off = 1; off < 64; off <<= 1) {
        int y = __shfl_up(x, off);
        if (lane >= off) x += y;
    }
    __shared__ int s16[16];
    if (lane == 63) s16[w] = x;
    __syncthreads();
    if (w == 0) {
        int y = (lane < 16) ? s16[lane] : 0;
#pragma unroll
        for (int off = 1; off < 16; off <<= 1) {
            int z = __shfl_up(y, off);
            if (lane >= off) y += z;
        }
        if (lane < 16) s16[lane] = y;
    }
    __syncthreads();
    if (w > 0) x += s16[w - 1];
    if (t < nb) bsum[t] = x;
}

__global__ __launch_bounds__(256) void scan3_kernel(const int* __restrict__ scanned,
                                                    const int* __restrict__ bsum,
                                                    int* __restrict__ rowptr, int N) {
    int t = blockIdx.x * 256 + threadIdx.x;
    if (t >= N) return;
    int add = (blockIdx.x > 0) ? bsum[blockIdx.x - 1] : 0;
    rowptr[t + 1] = scanned[t] + add;
    if (t == 0) rowptr[0] = 0;
}

// atomic-free fill: slot = rowptr[dst] + rank; stores {src, ew}
__global__ __launch_bounds__(256) void fill_kernel(const float* __restrict__ ea,
                                                   const int* __restrict__ src,
                                                   const int* __restrict__ dst,
                                                   const int* __restrict__ rank,
                                                   const float* __restrict__ We,
                                                   const float* __restrict__ be,
                                                   const int* __restrict__ rowptr,
                                                   float2* __restrict__ srcnorm, int E) {
    int e = blockIdx.x * blockDim.x + threadIdx.x;
    if (e >= E) return;
    float ew = ea[e] * We[0] + be[0];
    int d = dst[e];
    srcnorm[rowptr[d] + rank[e]] = make_float2(__int_as_float(src[e]), ew);
}

// ============ input proj: h1 = relu(x@Win+b) (f32) and hs1 = h1*dinv (bf16) ============

__global__ __launch_bounds__(256) void inproj_kernel(const float* __restrict__ x,
                                                     const float* __restrict__ W,
                                                     const float* __restrict__ b,
                                                     const float* __restrict__ dinv,
                                                     float* __restrict__ h,
                                                     unsigned* __restrict__ hs, int N) {
    int lane = threadIdx.x & 63;
    int gw = (blockIdx.x * 256 + threadIdx.x) >> 6;
    int n0 = gw * 4;
    if (n0 >= N) return;
    const float* xr[4];
    float acc[4], dnv[4];
    float bc = b[lane];
#pragma unroll
    for (int j = 0; j < 4; ++j) {
        int n = n0 + j; if (n >= N) n = N - 1;
        xr[j] = x + (long)__builtin_amdgcn_readfirstlane(n) * DIN;  // uniform -> s_load
        acc[j] = bc;
        dnv[j] = dinv[n];
    }
#pragma unroll 16
    for (int k = 0; k < DIN; ++k) {
        float wv = W[k * HID + lane];
#pragma unroll
        for (int j = 0; j < 4; ++j)
            acc[j] = fmaf(xr[j][k], wv, acc[j]);
    }
#pragma unroll
    for (int j = 0; j < 4; ++j) {
        int n = n0 + j;
        if (n < N) {
            float hv = fmaxf(acc[j], 0.0f);
            h[((long)n << 6) | lane] = hv;
            unsigned bv = f2bf(hv * dnv[j]);
            unsigned nb = __shfl_xor(bv, 1);
            if ((lane & 1) == 0)
                hs[(unsigned)n * 32 + (lane >> 1)] = bv | (nb << 16);
        }
    }
}

// ============ pure gather: s[n] = dinv[n]*(sum ew*hs[src] + hs[n]) ============

__global__ __launch_bounds__(256) void gather_kernel(const int* __restrict__ rowptr,
                                                     const float2* __restrict__ srcnorm,
                                                     const unsigned* __restrict__ hs,
                                                     const float* __restrict__ dinv,
                                                     float* __restrict__ s, int N) {
    int t = blockIdx.x * blockDim.x + threadIdx.x;
    int lane = t & 63;
    int c2 = lane & 31, hf = lane >> 5;
    int n = __builtin_amdgcn_readfirstlane(t >> 6);   // wave-uniform node id
    if (n >= N) return;
    unsigned sv = hs[(unsigned)n * 32 + c2];
    float ax = hf ? 0.0f : bflo(sv);                  // self term, half 0 only
    float ay = hf ? 0.0f : bfhi(sv);
    int beg = rowptr[n], end = rowptr[n + 1];         // uniform -> s_load
    int i = beg;
    int end16 = beg + ((end - beg) & ~15);
    for (; i < end16; i += 16) {                      // 16 edges: 8 per half
        float2 p0 = srcnorm[i + hf],      p1 = srcnorm[i + 2 + hf];
        float2 p2 = srcnorm[i + 4 + hf],  p3 = srcnorm[i + 6 + hf];
        float2 p4 = srcnorm[i + 8 + hf],  p5 = srcnorm[i + 10 + hf];
        float2 p6 = srcnorm[i + 12 + hf], p7 = srcnorm[i + 14 + hf];
        unsigned v0 = hs[(unsigned)__float_as_int(p0.x) * 32 + c2];
        unsigned v1 = hs[(unsigned)__float_as_int(p1.x) * 32 + c2];
        unsigned v2 = hs[(unsigned)__float_as_int(p2.x) * 32 + c2];
        unsigned v3 = hs[(unsigned)__float_as_int(p3.x) * 32 + c2];
        unsigned v4 = hs[(unsigned)__float_as_int(p4.x) * 32 + c2];
        unsigned v5 = hs[(unsigned)__float_as_int(p5.x) * 32 + c2];
        unsigned v6 = hs[(unsigned)__float_as_int(p6.x) * 32 + c2];
        unsigned v7 = hs[(unsigned)__float_as_int(p7.x) * 32 + c2];
        ax = fmaf(bflo(v0), p0.y, ax); ay = fmaf(bfhi(v0), p0.y, ay);
        ax = fmaf(bflo(v1), p1.y, ax); ay = fmaf(bfhi(v1), p1.y, ay);
        ax = fmaf(bflo(v2), p2.y, ax); ay = fmaf(bfhi(v2), p2.y, ay);
        ax = fmaf(bflo(v3), p3.y, ax); ay = fmaf(bfhi(v3), p3.y, ay);
        ax = fmaf(bflo(v4), p4.y, ax); ay = fmaf(bfhi(v4), p4.y, ay);
        ax = fmaf(bflo(v5), p5.y, ax); ay = fmaf(bfhi(v5), p5.y, ay);
        ax = fmaf(bflo(v6), p6.y, ax); ay = fmaf(bfhi(v6), p6.y, ay);
        ax = fmaf(bflo(v7), p7.y, ax); ay = fmaf(bfhi(v7), p7.y, ay);
    }
    int end8 = i + ((end - i) & ~7);
    for (; i < end8; i += 8) {
        float2 pa = srcnorm[i + hf],     pb = srcnorm[i + 2 + hf];
        float2 pc = srcnorm[i + 4 + hf], pd = srcnorm[i + 6 + hf];
        unsigned va = hs[(unsigned)__float_as_int(pa.x) * 32 + c2];
        unsigned vb = hs[(unsigned)__float_as_int(pb.x) * 32 + c2];
        unsigned vc = hs[(unsigned)__float_as_int(pc.x) * 32 + c2];
        unsigned vd = hs[(unsigned)__float_as_int(pd.x) * 32 + c2];
        ax = fmaf(bflo(va), pa.y, ax); ay = fmaf(bfhi(va), pa.y, ay);
        ax = fmaf(bflo(vb), pb.y, ax); ay = fmaf(bfhi(vb), pb.y, ay);
        ax = fmaf(bflo(vc), pc.y, ax); ay = fmaf(bfhi(vc), pc.y, ay);
        ax = fmaf(bflo(vd), pd.y, ax); ay = fmaf(bfhi(vd), pd.y, ay);
    }
    for (; i < end; i += 2) {
        int ia = i + hf;
        if (ia < end) {
            float2 p = srcnorm[ia];
            unsigned v = hs[(unsigned)__float_as_int(p.x) * 32 + c2];
            ax = fmaf(bflo(v), p.y, ax);
            ay = fmaf(bfhi(v), p.y, ay);
        }
    }
    ax += __shfl_xor(ax, 32);                         // combine halves
    ay += __shfl_xor(ay, 32);
    if (hf == 0) {
        float dn = dinv[n];
        ((float2*)(s + ((long)n << 6)))[c2] = make_float2(ax * dn, ay * dn);
    }
}

// ============ dense layer: out = LN(s@W + b) relu (+res) -> h [, hs_next] ============

__global__ __launch_bounds__(256) void dense_kernel(const float* __restrict__ s,
                                                    const float* __restrict__ Wg,
                                                    const float* __restrict__ bg,
                                                    const float* __restrict__ dinv,
                                                    float* __restrict__ h,
                                                    unsigned* __restrict__ hs,
                                                    int add_res, int N) {
    int lane = threadIdx.x & 63;
    int gw = blockIdx.x * 4 + ((int)threadIdx.x >> 6);
    int nw = gridDim.x * 4;
    int withhs = (hs != nullptr);
    float wcol[64];
#pragma unroll
    for (int k = 0; k < 64; ++k) wcol[k] = Wg[k * HID + lane];
    float bgl = bg[lane];
    for (int n0 = gw * 4; n0 < N; n0 += nw * 4) {
        float sv[4], acc[4], rv[4], dnv[4];
#pragma unroll
        for (int j = 0; j < 4; ++j) {
            int n = n0 + j; if (n >= N) n = N - 1;
            sv[j] = s[((long)n << 6) | lane];
            rv[j] = add_res ? h[((long)n << 6) | lane] : 0.0f;
            dnv[j] = withhs ? dinv[n] : 0.0f;
            acc[j] = bgl;
        }
#pragma unroll
        for (int k = 0; k < 64; ++k) {
#pragma unroll
            for (int j = 0; j < 4; ++j)
                acc[j] = fmaf(bcast(sv[j], k), wcol[k], acc[j]);
        }
        float s1[4], s2[4];
#pragma unroll
        for (int j = 0; j < 4; ++j) { s1[j] = acc[j]; s2[j] = acc[j] * acc[j]; }
#pragma unroll
        for (int off = 32; off; off >>= 1) {
#pragma unroll
            for (int j = 0; j < 4; ++j) {
                s1[j] += __shfl_xor(s1[j], off);
                s2[j] += __shfl_xor(s2[j], off);
            }
        }
#pragma unroll
        for (int j = 0; j < 4; ++j) {
            int n = n0 + j;
            float mean = s1[j] * (1.0f / 64.0f);
            float var  = s2[j] * (1.0f / 64.0f) - mean * mean;
            float o = fmaxf((acc[j] - mean) * rsqrtf(var + 1e-5f), 0.0f) + rv[j];
            if (n < N) {
                h[((long)n << 6) | lane] = o;
                if (withhs) {
                    unsigned bv = f2bf(o * dnv[j]);
                    unsigned nb = __shfl_xor(bv, 1);
                    if ((lane & 1) == 0)
                        hs[(unsigned)n * 32 + (lane >> 1)] = bv | (nb << 16);
                }
            }
        }
    }
}

// ============ fused heads: weights in registers, grid-stride ============

__global__ __launch_bounds__(256) void head_kernel(const float* __restrict__ h,
                                                   const float* __restrict__ Wa1,
                                                   const float* __restrict__ ba1,
                                                   const float* __restrict__ Wa2,
                                                   const float* __restrict__ ba2,
                                                   const float* __restrict__ Wc1,
                                                   const float* __restrict__ bc1,
                                                   const float* __restrict__ Wc2,
                                                   const float* __restrict__ bc2,
                                                   float* __restrict__ out, int N) {
    __shared__ float hsm[4][HID];
    int lane = threadIdx.x & 63, w = threadIdx.x >> 6;
    int jj = lane & 31, hf = lane >> 5;
    float wa1[32], wc1[32];
#pragma unroll
    for (int k = 0; k < 32; ++k) {
        int kk = hf * 32 + k;
        wa1[k] = Wa1[kk * 32 + jj];
        wc1[k] = Wc1[kk * 32 + jj];
    }
    float wa2v = Wa2[jj], ba1v = ba1[jj], ba2v = ba2[0], bc1v = bc1[jj];
    float wc2v[4], bc2v[4];
#pragma unroll
    for (int c = 0; c < 4; ++c) { wc2v[c] = Wc2[jj * 4 + c]; bc2v[c] = bc2[c]; }
    int gw = blockIdx.x * 4 + w, stride = gridDim.x * 4;
    for (int n = gw; n < N; n += stride) {
        float hv = h[((long)n << 6) | lane];
        hsm[w][lane] = hv;
        float a1p = 0.0f, c1p = 0.0f;
#pragma unroll
        for (int k = 0; k < 32; ++k) {
            float hk = hsm[w][hf * 32 + k];
            a1p = fmaf(hk, wa1[k], a1p);
            c1p = fmaf(hk, wc1[k], c1p);
        }
        a1p += __shfl_xor(a1p, 32);
        c1p += __shfl_xor(c1p, 32);
        float a1 = fmaxf(a1p + ba1v, 0.0f);
        float z = a1 * wa2v;
#pragma unroll
        for (int off = 16; off; off >>= 1) z += __shfl_xor(z, off);
        float attn = 1.0f / (1.0f + expf(-(z + ba2v)));
        float c1 = fmaxf(fmaf(attn, c1p, bc1v), 0.0f);
        float o0 = c1 * wc2v[0], o1 = c1 * wc2v[1], o2 = c1 * wc2v[2], o3 = c1 * wc2v[3];
#pragma unroll
        for (int off = 16; off; off >>= 1) {
            o0 += __shfl_xor(o0, off);
            o1 += __shfl_xor(o1, off);
            o2 += __shfl_xor(o2, off);
            o3 += __shfl_xor(o3, off);
        }
        if (lane == 0) {
            float4 ov = make_float4(o0 + bc2v[0], o1 + bc2v[1], o2 + bc2v[2], o3 + bc2v[3]);
            *(float4*)(out + (long)n * NCLS) = ov;
            out[(long)N * NCLS + n] = attn;
        }
    }
}

// ============ launcher ============

extern "C" void kernel_launch(void* const* d_in, const int* in_sizes, int n_in,
                              void* d_out, int out_size, void* d_ws, size_t ws_size,
                              hipStream_t stream) {
    const float* x    = (const float*)d_in[0];
    const float* ea   = (const float*)d_in[1];
    const int*   ei   = (const int*)d_in[2];
    const float* We   = (const float*)d_in[3];
    const float* be   = (const float*)d_in[4];
    const float* W_in = (const float*)d_in[5];
    const float* b_in = (const float*)d_in[6];
    const float* W_g  = (const float*)d_in[7];
    const float* b_g  = (const float*)d_in[8];
    const float* Wa1  = (const float*)d_in[9];
    const float* ba1  = (const float*)d_in[10];
    const float* Wa2  = (const float*)d_in[11];
    const float* ba2  = (const float*)d_in[12];
    const float* Wc1  = (const float*)d_in[13];
    const float* bc1  = (const float*)d_in[14];
    const float* Wc2  = (const float*)d_in[15];
    const float* bc2  = (const float*)d_in[16];
    float* out = (float*)d_out;

    const int N = in_sizes[0] / DIN;       // 100000
    const int E = in_sizes[1];             // 1600000
    const int* srcI = ei;
    const int* dstI = ei + E;
    const int nblk = (N + 255) / 256;      // 391 <= 1024

    unsigned long long* pk = (unsigned long long*)d_ws;     // N u64
    float*    dinv    = (float*)(pk + N);                   // N f32
    float*    h       = dinv + N;                           // N*64 f32
    float*    s       = h + (long)N * HID;                  // N*64 f32
    unsigned* hs      = (unsigned*)(s + (long)N * HID);     // N*32 u32 (bf16 pairs)
    float2*   srcnorm = (float2*)(hs + (long)N * 32);       // E float2 (8B-aligned)
    int*      scanned = (int*)(srcnorm + E);                // N
    int*      bsum    = scanned + N;                        // 1024
    int*      rowptr  = bsum + 1024;                        // N+1
    int*      rank    = rowptr + N + 1;                     // E

    hipMemsetAsync(pk, 0, N * sizeof(unsigned long long), stream);

    degrank_kernel<<<(E + 255) / 256, 256, 0, stream>>>(ea, dstI, We, be, pk, rank, E);
    unpack_scan1_kernel<<<nblk, 256, 0, stream>>>(pk, dinv, scanned, bsum, N);
    scan2_kernel<<<1, 1024, 0, stream>>>(bsum, nblk);
    scan3_kernel<<<nblk, 256, 0, stream>>>(scanned, bsum, rowptr, N);
    fill_kernel<<<(E + 255) / 256, 256, 0, stream>>>(ea, srcI, dstI, rank, We, be,
                                                     rowptr, srcnorm, E);

    inproj_kernel<<<(N + 15) / 16, 256, 0, stream>>>(x, W_in, b_in, dinv, h, hs, N);

    long nt = (long)N * HID;
    // layer 0: gather(hs1) -> s ; dense: LN(s@W0+b0) -> h2, hs2 (no residual)
    gather_kernel<<<(nt + 255) / 256, 256, 0, stream>>>(rowptr, srcnorm, hs, dinv, s, N);
    dense_kernel<<<1024, 256, 0, stream>>>(s, W_g, b_g, dinv, h, hs, 0, N);
    // layer 1: residual
    gather_kernel<<<(nt + 255) / 256, 256, 0, stream>>>(rowptr, srcnorm, hs, dinv, s, N);
    dense_kernel<<<1024, 256, 0, stream>>>(s, W_g + HID * HID, b_g + HID, dinv, h, hs, 1, N);
    // layer 2: dense (no hs), then standalone head
    gather_kernel<<<(nt + 255) / 256, 256, 0, stream>>>(rowptr, srcnorm, hs, dinv, s, N);
    dense_kernel<<<1024, 256, 0, stream>>>(s, W_g + 2 * HID * HID, b_g + 2 * HID, dinv,
                                           h, (unsigned*)nullptr, 1, N);
    head_kernel<<<1024, 256, 0, stream>>>(h, Wa1, ba1, Wa2, ba2,
                                          Wc1, bc1, Wc2, bc2, out, N);
}

// Round 16
// 373.825 us; speedup vs baseline: 1.2507x; 1.2306x over previous
//
#include <hip/hip_runtime.h>
#include <hip/hip_bf16.h>

#define HID 64
#define DIN 128
#define NCLS 4

typedef __attribute__((ext_vector_type(8))) __bf16 bf16x8;
typedef __attribute__((ext_vector_type(4))) float f32x4;

__device__ __forceinline__ ushort f2bf(float f) {            // fp32 -> bf16 RNE
    unsigned u = __float_as_uint(f);
    return (ushort)((u + 0x7fffu + ((u >> 16) & 1u)) >> 16);
}
__device__ __forceinline__ float bflo(unsigned v) { return __uint_as_float(v << 16); }
__device__ __forceinline__ float bfhi(unsigned v) { return __uint_as_float(v & 0xffff0000u); }

__device__ __forceinline__ bf16x8 cvt8(const float4* p) {    // 8 f32 -> bf16x8
    float4 a = p[0], c = p[1];
    union { ushort u[8]; bf16x8 v; } r;
    r.u[0] = f2bf(a.x); r.u[1] = f2bf(a.y); r.u[2] = f2bf(a.z); r.u[3] = f2bf(a.w);
    r.u[4] = f2bf(c.x); r.u[5] = f2bf(c.y); r.u[6] = f2bf(c.z); r.u[7] = f2bf(c.w);
    return r.v;
}

// ============ CSR build ============
// pk[d] packs {cnt:24 | deg_fp:40} (scale 2^20); one u64 atomic per edge,
// returned high bits = this edge's rank within its dst bucket.

__global__ __launch_bounds__(256) void degrank_kernel(const float* __restrict__ ea,
                                                      const int* __restrict__ dst,
                                                      const float* __restrict__ We,
                                                      const float* __restrict__ be,
                                                      unsigned long long* __restrict__ pk,
                                                      int* __restrict__ rank, int E) {
    int e = blockIdx.x * blockDim.x + threadIdx.x;
    if (e >= E) return;
    float ew = ea[e] * We[0] + be[0];
    unsigned long long fx = (unsigned long long)(ew * 1048576.0f + 0.5f);
    unsigned long long old = atomicAdd(&pk[dst[e]], (1ull << 40) | fx);
    rank[e] = (int)(old >> 40);
}

__global__ __launch_bounds__(256) void unpack_scan1_kernel(const unsigned long long* __restrict__ pk,
                                                           float* __restrict__ dinv,
                                                           int* __restrict__ scanned,
                                                           int* __restrict__ bsum, int N) {
    int t = blockIdx.x * 256 + threadIdx.x;
    int lane = threadIdx.x & 63, w = threadIdx.x >> 6;
    int cnt = 0;
    if (t < N) {
        unsigned long long v = pk[t];
        cnt = (int)(v >> 40);
        float deg = (float)((double)(v & ((1ull << 40) - 1)) * (1.0 / 1048576.0));
        dinv[t] = rsqrtf(deg + 1.0f);      // self-loop weight 1.0
    }
    int xv = cnt;
#pragma unroll
    for (int off = 1; off < 64; off <<= 1) {
        int y = __shfl_up(xv, off);
        if (lane >= off) xv += y;
    }
    __shared__ int ws_[4];
    if (lane == 63) ws_[w] = xv;
    __syncthreads();
    for (int i = 0; i < w; ++i) xv += ws_[i];
    if (t < N) scanned[t] = xv;
    if (threadIdx.x == 255) bsum[blockIdx.x] = xv;
}

__global__ __launch_bounds__(1024) void scan2_kernel(int* __restrict__ bsum, int nb) {
    int t = threadIdx.x, lane = t & 63, w = t >> 6;
    int x = (t < nb) ? bsum[t] : 0;
#pragma unroll
    for (int off = 1; off < 64; off <<= 1) {
        int y = __shfl_up(x, off);
        if (lane >= off) x += y;
    }
    __shared__ int s16[16];
    if (lane == 63) s16[w] = x;
    __syncthreads();
    if (w == 0) {
        int y = (lane < 16) ? s16[lane] : 0;
#pragma unroll
        for (int off = 1; off < 16; off <<= 1) {
            int z = __shfl_up(y, off);
            if (lane >= off) y += z;
        }
        if (lane < 16) s16[lane] = y;
    }
    __syncthreads();
    if (w > 0) x += s16[w - 1];
    if (t < nb) bsum[t] = x;
}

__global__ __launch_bounds__(256) void scan3_kernel(const int* __restrict__ scanned,
                                                    const int* __restrict__ bsum,
                                                    int* __restrict__ rowptr, int N) {
    int t = blockIdx.x * 256 + threadIdx.x;
    if (t >= N) return;
    int add = (blockIdx.x > 0) ? bsum[blockIdx.x - 1] : 0;
    rowptr[t + 1] = scanned[t] + add;
    if (t == 0) rowptr[0] = 0;
}

// atomic-free fill: slot = rowptr[dst] + rank; stores {src, ew}
__global__ __launch_bounds__(256) void fill_kernel(const float* __restrict__ ea,
                                                   const int* __restrict__ src,
                                                   const int* __restrict__ dst,
                                                   const int* __restrict__ rank,
                                                   const float* __restrict__ We,
                                                   const float* __restrict__ be,
                                                   const int* __restrict__ rowptr,
                                                   float2* __restrict__ srcnorm, int E) {
    int e = blockIdx.x * blockDim.x + threadIdx.x;
    if (e >= E) return;
    float ew = ea[e] * We[0] + be[0];
    int d = dst[e];
    srcnorm[rowptr[d] + rank[e]] = make_float2(__int_as_float(src[e]), ew);
}

// ============ input proj (MFMA): h1 = relu(x@Win+b), hs1 = h1*dinv (bf16) ============
// Wave = 16 nodes. A: lane holds x[n0+(l&15)][kg*8..+7] per k-step (bf16).
// B: W^T bf16 in LDS (row pad +8). C/D: col=lane&15, row=(lane>>4)*4+reg.

__global__ __launch_bounds__(256) void inproj_mfma_kernel(const float* __restrict__ x,
                                                          const float* __restrict__ W,
                                                          const float* __restrict__ b,
                                                          const float* __restrict__ dinv,
                                                          float* __restrict__ h,
                                                          unsigned* __restrict__ hs, int N) {
    __shared__ ushort Wt[64][DIN + 8];                 // W^T bf16, padded
    for (int idx = threadIdx.x; idx < DIN * HID; idx += 256) {
        int k = idx >> 6, c = idx & 63;
        Wt[c][k] = f2bf(W[idx]);
    }
    __syncthreads();
    int lane = threadIdx.x & 63;
    int l15 = lane & 15, kg = lane >> 4;
    int wv = blockIdx.x * 4 + ((int)threadIdx.x >> 6);
    int n0 = wv * 16;
    if (n0 >= N) return;
    int ar = n0 + l15; if (ar >= N) ar = N - 1;
    const float* xr = x + (long)ar * DIN;
    f32x4 z = {0.0f, 0.0f, 0.0f, 0.0f};
    f32x4 acc[4] = {z, z, z, z};
#pragma unroll
    for (int ks = 0; ks < 4; ++ks) {
        bf16x8 af = cvt8((const float4*)(xr + ks * 32 + kg * 8));
#pragma unroll
        for (int ct = 0; ct < 4; ++ct) {
            bf16x8 bfr = *(const bf16x8*)&Wt[ct * 16 + l15][ks * 32 + kg * 8];
            acc[ct] = __builtin_amdgcn_mfma_f32_16x16x32_bf16(af, bfr, acc[ct], 0, 0, 0);
        }
    }
    float bgv[4];
#pragma unroll
    for (int ct = 0; ct < 4; ++ct) bgv[ct] = b[ct * 16 + l15];
#pragma unroll
    for (int r = 0; r < 4; ++r) {
        int n = n0 + kg * 4 + r;
        bool ok = (n < N);
        float dn = ok ? dinv[n] : 0.0f;
#pragma unroll
        for (int ct = 0; ct < 4; ++ct) {
            int c = ct * 16 + l15;
            float o = fmaxf(acc[ct][r] + bgv[ct], 0.0f);
            if (ok) h[((long)n << 6) | c] = o;
            unsigned bv = f2bf(o * dn);
            unsigned nb = __shfl_xor(bv, 1);
            if (ok && (l15 & 1) == 0)
                hs[(unsigned)n * 32 + ct * 8 + (l15 >> 1)] = bv | (nb << 16);
        }
    }
}

// ============ pure gather: s[n] = dinv[n]*(sum ew*hs[src] + hs[n]) (bf16 out) ============

__global__ __launch_bounds__(256) void gather_kernel(const int* __restrict__ rowptr,
                                                     const float2* __restrict__ srcnorm,
                                                     const unsigned* __restrict__ hs,
                                                     const float* __restrict__ dinv,
                                                     unsigned* __restrict__ sb, int N) {
    int t = blockIdx.x * blockDim.x + threadIdx.x;
    int lane = t & 63;
    int c2 = lane & 31, hf = lane >> 5;
    int n = __builtin_amdgcn_readfirstlane(t >> 6);   // wave-uniform node id
    if (n >= N) return;
    unsigned sv = hs[(unsigned)n * 32 + c2];
    float ax = hf ? 0.0f : bflo(sv);                  // self term, half 0 only
    float ay = hf ? 0.0f : bfhi(sv);
    int beg = rowptr[n], end = rowptr[n + 1];         // uniform -> s_load
    int i = beg;
    int end16 = beg + ((end - beg) & ~15);
    for (; i < end16; i += 16) {                      // 16 edges: 8 per half
        float2 p0 = srcnorm[i + hf],      p1 = srcnorm[i + 2 + hf];
        float2 p2 = srcnorm[i + 4 + hf],  p3 = srcnorm[i + 6 + hf];
        float2 p4 = srcnorm[i + 8 + hf],  p5 = srcnorm[i + 10 + hf];
        float2 p6 = srcnorm[i + 12 + hf], p7 = srcnorm[i + 14 + hf];
        unsigned v0 = hs[(unsigned)__float_as_int(p0.x) * 32 + c2];
        unsigned v1 = hs[(unsigned)__float_as_int(p1.x) * 32 + c2];
        unsigned v2 = hs[(unsigned)__float_as_int(p2.x) * 32 + c2];
        unsigned v3 = hs[(unsigned)__float_as_int(p3.x) * 32 + c2];
        unsigned v4 = hs[(unsigned)__float_as_int(p4.x) * 32 + c2];
        unsigned v5 = hs[(unsigned)__float_as_int(p5.x) * 32 + c2];
        unsigned v6 = hs[(unsigned)__float_as_int(p6.x) * 32 + c2];
        unsigned v7 = hs[(unsigned)__float_as_int(p7.x) * 32 + c2];
        ax = fmaf(bflo(v0), p0.y, ax); ay = fmaf(bfhi(v0), p0.y, ay);
        ax = fmaf(bflo(v1), p1.y, ax); ay = fmaf(bfhi(v1), p1.y, ay);
        ax = fmaf(bflo(v2), p2.y, ax); ay = fmaf(bfhi(v2), p2.y, ay);
        ax = fmaf(bflo(v3), p3.y, ax); ay = fmaf(bfhi(v3), p3.y, ay);
        ax = fmaf(bflo(v4), p4.y, ax); ay = fmaf(bfhi(v4), p4.y, ay);
        ax = fmaf(bflo(v5), p5.y, ax); ay = fmaf(bfhi(v5), p5.y, ay);
        ax = fmaf(bflo(v6), p6.y, ax); ay = fmaf(bfhi(v6), p6.y, ay);
        ax = fmaf(bflo(v7), p7.y, ax); ay = fmaf(bfhi(v7), p7.y, ay);
    }
    int end8 = i + ((end - i) & ~7);
    for (; i < end8; i += 8) {
        float2 pa = srcnorm[i + hf],     pb = srcnorm[i + 2 + hf];
        float2 pc = srcnorm[i + 4 + hf], pd = srcnorm[i + 6 + hf];
        unsigned va = hs[(unsigned)__float_as_int(pa.x) * 32 + c2];
        unsigned vb = hs[(unsigned)__float_as_int(pb.x) * 32 + c2];
        unsigned vc = hs[(unsigned)__float_as_int(pc.x) * 32 + c2];
        unsigned vd = hs[(unsigned)__float_as_int(pd.x) * 32 + c2];
        ax = fmaf(bflo(va), pa.y, ax); ay = fmaf(bfhi(va), pa.y, ay);
        ax = fmaf(bflo(vb), pb.y, ax); ay = fmaf(bfhi(vb), pb.y, ay);
        ax = fmaf(bflo(vc), pc.y, ax); ay = fmaf(bfhi(vc), pc.y, ay);
        ax = fmaf(bflo(vd), pd.y, ax); ay = fmaf(bfhi(vd), pd.y, ay);
    }
    for (; i < end; i += 2) {
        int ia = i + hf;
        if (ia < end) {
            float2 p = srcnorm[ia];
            unsigned v = hs[(unsigned)__float_as_int(p.x) * 32 + c2];
            ax = fmaf(bflo(v), p.y, ax);
            ay = fmaf(bfhi(v), p.y, ay);
        }
    }
    ax += __shfl_xor(ax, 32);                         // combine halves
    ay += __shfl_xor(ay, 32);
    if (hf == 0) {
        float dn = dinv[n];
        sb[(unsigned)n * 32 + c2] = (unsigned)f2bf(ax * dn) |
                                    ((unsigned)f2bf(ay * dn) << 16);
    }
}

// ============ dense layer (MFMA): out = LN(s@W+b) relu (+res) -> h [, hs] ============

__global__ __launch_bounds__(256) void dense_mfma_kernel(const unsigned* __restrict__ sb,
                                                         const float* __restrict__ Wg,
                                                         const float* __restrict__ bg,
                                                         const float* __restrict__ dinv,
                                                         float* __restrict__ h,
                                                         unsigned* __restrict__ hs,
                                                         int add_res, int N) {
    __shared__ ushort Wt[64][HID + 8];                 // W^T bf16, padded
    for (int idx = threadIdx.x; idx < HID * HID; idx += 256) {
        int k = idx >> 6, c = idx & 63;
        Wt[c][k] = f2bf(Wg[idx]);
    }
    __syncthreads();
    int lane = threadIdx.x & 63;
    int l15 = lane & 15, kg = lane >> 4;
    int wv = blockIdx.x * 4 + ((int)threadIdx.x >> 6);
    int n0 = wv * 16;
    if (n0 >= N) return;
    bf16x8 bfr[2][4];
#pragma unroll
    for (int ks = 0; ks < 2; ++ks)
#pragma unroll
        for (int ct = 0; ct < 4; ++ct)
            bfr[ks][ct] = *(const bf16x8*)&Wt[ct * 16 + l15][ks * 32 + kg * 8];
    int ar = n0 + l15; if (ar >= N) ar = N - 1;
    const uint4* sr = (const uint4*)(sb + (unsigned)ar * 32);
    bf16x8 af0 = __builtin_bit_cast(bf16x8, sr[kg]);       // k = kg*8   (ks=0)
    bf16x8 af1 = __builtin_bit_cast(bf16x8, sr[4 + kg]);   // k = 32+kg*8 (ks=1)
    f32x4 z = {0.0f, 0.0f, 0.0f, 0.0f};
    f32x4 acc[4];
#pragma unroll
    for (int ct = 0; ct < 4; ++ct) {
        acc[ct] = __builtin_amdgcn_mfma_f32_16x16x32_bf16(af0, bfr[0][ct], z, 0, 0, 0);
        acc[ct] = __builtin_amdgcn_mfma_f32_16x16x32_bf16(af1, bfr[1][ct], acc[ct], 0, 0, 0);
    }
    float bgv[4];
#pragma unroll
    for (int ct = 0; ct < 4; ++ct) bgv[ct] = bg[ct * 16 + l15];
#pragma unroll
    for (int ct = 0; ct < 4; ++ct)
#pragma unroll
        for (int r = 0; r < 4; ++r) acc[ct][r] += bgv[ct];
    // LN over 64 cols of each row (4 ct-values/lane, reduce across 16 lanes)
    float s1[4], s2[4];
#pragma unroll
    for (int r = 0; r < 4; ++r) {
        s1[r] = acc[0][r] + acc[1][r] + acc[2][r] + acc[3][r];
        s2[r] = acc[0][r] * acc[0][r] + acc[1][r] * acc[1][r] +
                acc[2][r] * acc[2][r] + acc[3][r] * acc[3][r];
    }
#pragma unroll
    for (int off = 1; off < 16; off <<= 1) {
#pragma unroll
        for (int r = 0; r < 4; ++r) {
            s1[r] += __shfl_xor(s1[r], off);
            s2[r] += __shfl_xor(s2[r], off);
        }
    }
    int withhs = (hs != nullptr);
#pragma unroll
    for (int r = 0; r < 4; ++r) {
        int n = n0 + kg * 4 + r;
        bool ok = (n < N);
        float mean = s1[r] * (1.0f / 64.0f);
        float var  = s2[r] * (1.0f / 64.0f) - mean * mean;
        float rsq  = rsqrtf(var + 1e-5f);
        float dn = (withhs && ok) ? dinv[n] : 0.0f;
#pragma unroll
        for (int ct = 0; ct < 4; ++ct) {
            int c = ct * 16 + l15;
            long idx = ((long)n << 6) | c;
            float o = fmaxf((acc[ct][r] - mean) * rsq, 0.0f);
            if (add_res && ok) o += h[idx];
            if (ok) h[idx] = o;
            if (withhs) {
                unsigned bv = f2bf(o * dn);
                unsigned nb = __shfl_xor(bv, 1);
                if (ok && (l15 & 1) == 0)
                    hs[(unsigned)n * 32 + ct * 8 + (l15 >> 1)] = bv | (nb << 16);
            }
        }
    }
}

// ============ fused heads: weights in registers, grid-stride ============

__global__ __launch_bounds__(256) void head_kernel(const float* __restrict__ h,
                                                   const float* __restrict__ Wa1,
                                                   const float* __restrict__ ba1,
                                                   const float* __restrict__ Wa2,
                                                   const float* __restrict__ ba2,
                                                   const float* __restrict__ Wc1,
                                                   const float* __restrict__ bc1,
                                                   const float* __restrict__ Wc2,
                                                   const float* __restrict__ bc2,
                                                   float* __restrict__ out, int N) {
    __shared__ float hsm[4][HID];
    int lane = threadIdx.x & 63, w = threadIdx.x >> 6;
    int jj = lane & 31, hf = lane >> 5;
    float wa1[32], wc1[32];
#pragma unroll
    for (int k = 0; k < 32; ++k) {
        int kk = hf * 32 + k;
        wa1[k] = Wa1[kk * 32 + jj];
        wc1[k] = Wc1[kk * 32 + jj];
    }
    float wa2v = Wa2[jj], ba1v = ba1[jj], ba2v = ba2[0], bc1v = bc1[jj];
    float wc2v[4], bc2v[4];
#pragma unroll
    for (int c = 0; c < 4; ++c) { wc2v[c] = Wc2[jj * 4 + c]; bc2v[c] = bc2[c]; }
    int gw = blockIdx.x * 4 + w, stride = gridDim.x * 4;
    for (int n = gw; n < N; n += stride) {
        float hv = h[((long)n << 6) | lane];
        hsm[w][lane] = hv;
        float a1p = 0.0f, c1p = 0.0f;
#pragma unroll
        for (int k = 0; k < 32; ++k) {
            float hk = hsm[w][hf * 32 + k];
            a1p = fmaf(hk, wa1[k], a1p);
            c1p = fmaf(hk, wc1[k], c1p);
        }
        a1p += __shfl_xor(a1p, 32);
        c1p += __shfl_xor(c1p, 32);
        float a1 = fmaxf(a1p + ba1v, 0.0f);
        float z = a1 * wa2v;
#pragma unroll
        for (int off = 16; off; off >>= 1) z += __shfl_xor(z, off);
        float attn = 1.0f / (1.0f + expf(-(z + ba2v)));
        float c1 = fmaxf(fmaf(attn, c1p, bc1v), 0.0f);
        float o0 = c1 * wc2v[0], o1 = c1 * wc2v[1], o2 = c1 * wc2v[2], o3 = c1 * wc2v[3];
#pragma unroll
        for (int off = 16; off; off >>= 1) {
            o0 += __shfl_xor(o0, off);
            o1 += __shfl_xor(o1, off);
            o2 += __shfl_xor(o2, off);
            o3 += __shfl_xor(o3, off);
        }
        if (lane == 0) {
            float4 ov = make_float4(o0 + bc2v[0], o1 + bc2v[1], o2 + bc2v[2], o3 + bc2v[3]);
            *(float4*)(out + (long)n * NCLS) = ov;
            out[(long)N * NCLS + n] = attn;
        }
    }
}

// ============ launcher ============

extern "C" void kernel_launch(void* const* d_in, const int* in_sizes, int n_in,
                              void* d_out, int out_size, void* d_ws, size_t ws_size,
                              hipStream_t stream) {
    const float* x    = (const float*)d_in[0];
    const float* ea   = (const float*)d_in[1];
    const int*   ei   = (const int*)d_in[2];
    const float* We   = (const float*)d_in[3];
    const float* be   = (const float*)d_in[4];
    const float* W_in = (const float*)d_in[5];
    const float* b_in = (const float*)d_in[6];
    const float* W_g  = (const float*)d_in[7];
    const float* b_g  = (const float*)d_in[8];
    const float* Wa1  = (const float*)d_in[9];
    const float* ba1  = (const float*)d_in[10];
    const float* Wa2  = (const float*)d_in[11];
    const float* ba2  = (const float*)d_in[12];
    const float* Wc1  = (const float*)d_in[13];
    const float* bc1  = (const float*)d_in[14];
    const float* Wc2  = (const float*)d_in[15];
    const float* bc2  = (const float*)d_in[16];
    float* out = (float*)d_out;

    const int N = in_sizes[0] / DIN;       // 100000
    const int E = in_sizes[1];             // 1600000
    const int* srcI = ei;
    const int* dstI = ei + E;
    const int nblk = (N + 255) / 256;      // 391 <= 1024
    const int mblk = ((N + 15) / 16 + 3) / 4;   // MFMA blocks: 4 waves x 16 nodes

    unsigned long long* pk = (unsigned long long*)d_ws;     // N u64
    float*    dinv    = (float*)(pk + N);                   // N f32
    float*    h       = dinv + N;                           // N*64 f32
    unsigned* sbuf    = (unsigned*)(h + (long)N * HID);     // N*32 u32 (bf16 pairs)
    unsigned* hs      = sbuf + (long)N * 32;                // N*32 u32 (bf16 pairs)
    float2*   srcnorm = (float2*)(hs + (long)N * 32);       // E float2 (8B-aligned)
    int*      scanned = (int*)(srcnorm + E);                // N
    int*      bsum    = scanned + N;                        // 1024
    int*      rowptr  = bsum + 1024;                        // N+1
    int*      rank    = rowptr + N + 1;                     // E

    hipMemsetAsync(pk, 0, N * sizeof(unsigned long long), stream);

    degrank_kernel<<<(E + 255) / 256, 256, 0, stream>>>(ea, dstI, We, be, pk, rank, E);
    unpack_scan1_kernel<<<nblk, 256, 0, stream>>>(pk, dinv, scanned, bsum, N);
    scan2_kernel<<<1, 1024, 0, stream>>>(bsum, nblk);
    scan3_kernel<<<nblk, 256, 0, stream>>>(scanned, bsum, rowptr, N);
    fill_kernel<<<(E + 255) / 256, 256, 0, stream>>>(ea, srcI, dstI, rank, We, be,
                                                     rowptr, srcnorm, E);

    inproj_mfma_kernel<<<mblk, 256, 0, stream>>>(x, W_in, b_in, dinv, h, hs, N);

    long nt = (long)N * HID;
    // layer 0: gather(hs1) -> s(bf16) ; dense: LN(s@W0+b0) -> h2, hs2
    gather_kernel<<<(nt + 255) / 256, 256, 0, stream>>>(rowptr, srcnorm, hs, dinv, sbuf, N);
    dense_mfma_kernel<<<mblk, 256, 0, stream>>>(sbuf, W_g, b_g, dinv, h, hs, 0, N);
    // layer 1: residual
    gather_kernel<<<(nt + 255) / 256, 256, 0, stream>>>(rowptr, srcnorm, hs, dinv, sbuf, N);
    dense_mfma_kernel<<<mblk, 256, 0, stream>>>(sbuf, W_g + HID * HID, b_g + HID, dinv,
                                                h, hs, 1, N);
    // layer 2: dense (no hs), then standalone head
    gather_kernel<<<(nt + 255) / 256, 256, 0, stream>>>(rowptr, srcnorm, hs, dinv, sbuf, N);
    dense_mfma_kernel<<<mblk, 256, 0, stream>>>(sbuf, W_g + 2 * HID * HID, b_g + 2 * HID,
                                                dinv, h, (unsigned*)nullptr, 1, N);
    head_kernel<<<1024, 256, 0, stream>>>(h, Wa1, ba1, Wa2, ba2,
                                          Wc1, bc1, Wc2, bc2, out, N);
}